// Round 14
// baseline (299.204 us; speedup 1.0000x reference)
//
#include <hip/hip_runtime.h>
#include <hip/hip_fp16.h>
#include <hip/hip_cooperative_groups.h>
#include <math.h>

namespace cg = cooperative_groups;

// GraphAttention: Q=4, N=50000, K=8, F_IN=128, F_OUT=64
// Primary: single cooperative kernel (512 blocks, grid.sync between phases).
// Fallback (if coop launch rejected): R11's 4 separate kernels.

#define FIN 128
#define FOUT 64
#define KN 8
#define CTXB 250            // chunks per q
#define CHUNK 200           // nodes per chunk
#define GRID 512            // cooperative grid: 2 blocks/CU guaranteed

typedef _Float16 f16x8 __attribute__((ext_vector_type(8)));
typedef float f32x4 __attribute__((ext_vector_type(4)));

// ================= cooperative mega-kernel =================
__global__ __launch_bounds__(256, 2) void k_mega(
        const float* __restrict__ query, const float* __restrict__ values,
        const int* __restrict__ edges, const float* __restrict__ W1,
        const float* __restrict__ b1, const float* __restrict__ W2,
        const float* __restrict__ b2, float* __restrict__ ctx,
        float* __restrict__ score, __half* __restrict__ y,
        float* __restrict__ s1, float* __restrict__ partial,
        float* __restrict__ zpart, int N, int Q) {
    cg::grid_group grid = cg::this_grid();
    __shared__ _Float16 Wlds[8192];    // 16 KB
    __shared__ float wlds[256];
    __shared__ float zred[4];
    __shared__ float4 part[256];
    __shared__ float red2[256];

    const int tid = threadIdx.x;
    const int bid = blockIdx.x;
    const int nBlocks = gridDim.x;
    const int wave = tid >> 6, lane = tid & 63;
    const int lg = lane >> 4, lr = lane & 15;
    const int unitsPerQ = (N + 15) / 16;
    const int totalUnits = unitsPerQ * Q;

    // ---- pack W1 -> LDS ----
    #pragma unroll
    for (int it = 0; it < 4; ++it) {
        int p = it * 256 + tid;
        int g6 = p >> 6;
        int kk = g6 >> 2, nt = g6 & 3;
        int lane6 = p & 63;
        int plg = lane6 >> 4, plr = lane6 & 15;
        int f = nt * 16 + plr;
        int kbase = kk * 32 + plg * 8;
        f16x8 fr;
        #pragma unroll
        for (int j = 0; j < 8; ++j)
            fr[j] = (_Float16)W1[(kbase + j) * FOUT + f];
        ((f16x8*)Wlds)[p] = fr;
    }
    __syncthreads();
    const f16x8* Bp = (const f16x8*)Wlds;

    // ===== Phase A: y = query @ W1 =====
    for (int u = bid * 4 + wave; u < totalUnits; u += nBlocks * 4) {
        int q = u / unitsPerQ, t = u % unitsPerQ;
        int base = t * 16;
        const float* qb = query + (size_t)q * N * FIN;
        __half* yq = y + (size_t)q * N * FOUT;
        int n0 = base + lr; if (n0 >= N) n0 = N - 1;
        const float4* r0 = (const float4*)(qb + (size_t)n0 * FIN);
        float4 a0[8];
        #pragma unroll
        for (int kk = 0; kk < 4; ++kk) {
            a0[2 * kk]     = r0[kk * 8 + lg * 2];
            a0[2 * kk + 1] = r0[kk * 8 + lg * 2 + 1];
        }
        f32x4 acc[4];
        #pragma unroll
        for (int nt = 0; nt < 4; ++nt) acc[nt] = (f32x4)0.f;
        #pragma unroll
        for (int kk = 0; kk < 4; ++kk) {
            f16x8 A0;
            const float* x0 = (const float*)&a0[2 * kk];
            #pragma unroll
            for (int j = 0; j < 8; ++j) A0[j] = (_Float16)x0[j];
            #pragma unroll
            for (int nt = 0; nt < 4; ++nt) {
                f16x8 Bf = Bp[(kk * 4 + nt) * 64 + lane];
                acc[nt] = __builtin_amdgcn_mfma_f32_16x16x32_f16(A0, Bf, acc[nt], 0, 0, 0);
            }
        }
        #pragma unroll
        for (int r = 0; r < 4; ++r) {
            int m0 = base + lg * 4 + r;
            if (m0 < N) {
                #pragma unroll
                for (int nt = 0; nt < 4; ++nt)
                    yq[(size_t)m0 * FOUT + nt * 16 + lr] = __float2half(acc[nt][r]);
            }
        }
    }
    grid.sync();

    // ===== Phase B: s1 =====
    {
        const int half = lane >> 5, fl = lane & 31;
        for (int u = bid; u < totalUnits; u += nBlocks) {
            int q = u / unitsPerQ, t = u % unitsPerQ;
            int nA = t * 16 + wave * 2 + half;
            int nB = nA + 8;
            int ncA = nA < N ? nA : N - 1;
            int ncB = nB < N ? nB : N - 1;
            const __half2* y2 = (const __half2*)(y + (size_t)q * N * FOUT);
            const int4* erA = (const int4*)(edges + (size_t)ncA * KN);
            const int4* erB = (const int4*)(edges + (size_t)ncB * KN);
            int4 eaA = erA[0], ebA = erA[1];
            int4 eaB = erB[0], ebB = erB[1];

            __half2 a0 = y2[(size_t)eaA.x * 32 + fl], a1 = y2[(size_t)eaA.y * 32 + fl];
            __half2 a2 = y2[(size_t)eaA.z * 32 + fl], a3 = y2[(size_t)eaA.w * 32 + fl];
            __half2 a4 = y2[(size_t)ebA.x * 32 + fl], a5 = y2[(size_t)ebA.y * 32 + fl];
            __half2 a6 = y2[(size_t)ebA.z * 32 + fl], a7 = y2[(size_t)ebA.w * 32 + fl];
            __half2 c0 = y2[(size_t)eaB.x * 32 + fl], c1 = y2[(size_t)eaB.y * 32 + fl];
            __half2 c2 = y2[(size_t)eaB.z * 32 + fl], c3 = y2[(size_t)eaB.w * 32 + fl];
            __half2 c4 = y2[(size_t)ebB.x * 32 + fl], c5 = y2[(size_t)ebB.y * 32 + fl];
            __half2 c6 = y2[(size_t)ebB.z * 32 + fl], c7 = y2[(size_t)ebB.w * 32 + fl];

            __half2 sA = __hadd2(__hadd2(__hadd2(a0, a1), __hadd2(a2, a3)),
                                 __hadd2(__hadd2(a4, a5), __hadd2(a6, a7)));
            __half2 sB = __hadd2(__hadd2(__hadd2(c0, c1), __hadd2(c2, c3)),
                                 __hadd2(__hadd2(c4, c5), __hadd2(c6, c7)));
            float2 fA = __half22float2(sA);
            float2 fB = __half22float2(sB);
            float2 bv = *(const float2*)(b1 + fl * 2);
            float2 wv = *(const float2*)(W2 + fl * 2);
            float xA0 = fA.x * 0.125f + bv.x, xA1 = fA.y * 0.125f + bv.y;
            float xB0 = fB.x * 0.125f + bv.x, xB1 = fB.y * 0.125f + bv.y;
            float eA0 = __expf(-2.f * fabsf(xA0)), eA1 = __expf(-2.f * fabsf(xA1));
            float eB0 = __expf(-2.f * fabsf(xB0)), eB1 = __expf(-2.f * fabsf(xB1));
            float tA0 = copysignf(__fdividef(1.f - eA0, 1.f + eA0), xA0);
            float tA1 = copysignf(__fdividef(1.f - eA1, 1.f + eA1), xA1);
            float tB0 = copysignf(__fdividef(1.f - eB0, 1.f + eB0), xB0);
            float tB1 = copysignf(__fdividef(1.f - eB1, 1.f + eB1), xB1);
            float pA = tA0 * wv.x + tA1 * wv.y;
            float pB = tB0 * wv.x + tB1 * wv.y;
            #pragma unroll
            for (int off = 16; off; off >>= 1) {
                pA += __shfl_xor(pA, off);
                pB += __shfl_xor(pB, off);
            }
            if (fl == 0) {
                float* s1q = s1 + (size_t)q * N;
                if (nA < N) s1q[nA] = pA;
                if (nB < N) s1q[nB] = pB;
            }
        }
    }
    grid.sync();

    // ===== Phase C: score + exp + Z + weighted values (grid-stride chunks) =====
    for (int c = bid; c < CTXB * Q; c += nBlocks) {
        const int q = c / CTXB, cb = c % CTXB;
        const int n0 = cb * CHUNK, n1 = min(n0 + CHUNK, N);
        const int cnt = n1 - n0;
        const float* s1q = s1 + (size_t)q * N;
        const float b2v = b2[0];

        float zp = 0.f;
        if (tid < cnt) {
            int n = n0 + tid;
            float acc = 0.f;
            #pragma unroll
            for (int k = 0; k < KN; ++k) acc += s1q[edges[(size_t)n * KN + k]];
            float sc = acc * 0.125f + b2v;
            score[(size_t)q * N + n] = sc;
            float ex = __expf(sc);
            wlds[tid] = ex;
            zp = ex;
        }
        float z = zp;
        #pragma unroll
        for (int off = 32; off; off >>= 1) z += __shfl_xor(z, off);
        if ((tid & 63) == 0) zred[tid >> 6] = z;
        __syncthreads();

        const int fi = tid & 31, g = tid >> 5;
        const float4* v = (const float4*)(values + (size_t)q * N * FIN);
        float4 acc = make_float4(0.f, 0.f, 0.f, 0.f);
        int n = n0 + g;
        for (; n + 56 < n1; n += 64) {
            int l = n - n0;
            float w0 = wlds[l],      w1 = wlds[l + 8],  w2 = wlds[l + 16], w3 = wlds[l + 24];
            float w4 = wlds[l + 32], w5 = wlds[l + 40], w6 = wlds[l + 48], w7 = wlds[l + 56];
            float4 v0 = v[(size_t)n * 32 + fi];
            float4 v1 = v[(size_t)(n + 8) * 32 + fi];
            float4 v2 = v[(size_t)(n + 16) * 32 + fi];
            float4 v3 = v[(size_t)(n + 24) * 32 + fi];
            float4 v4 = v[(size_t)(n + 32) * 32 + fi];
            float4 v5 = v[(size_t)(n + 40) * 32 + fi];
            float4 v6 = v[(size_t)(n + 48) * 32 + fi];
            float4 v7 = v[(size_t)(n + 56) * 32 + fi];
            acc.x = fmaf(w0, v0.x, acc.x); acc.y = fmaf(w0, v0.y, acc.y);
            acc.z = fmaf(w0, v0.z, acc.z); acc.w = fmaf(w0, v0.w, acc.w);
            acc.x = fmaf(w1, v1.x, acc.x); acc.y = fmaf(w1, v1.y, acc.y);
            acc.z = fmaf(w1, v1.z, acc.z); acc.w = fmaf(w1, v1.w, acc.w);
            acc.x = fmaf(w2, v2.x, acc.x); acc.y = fmaf(w2, v2.y, acc.y);
            acc.z = fmaf(w2, v2.z, acc.z); acc.w = fmaf(w2, v2.w, acc.w);
            acc.x = fmaf(w3, v3.x, acc.x); acc.y = fmaf(w3, v3.y, acc.y);
            acc.z = fmaf(w3, v3.z, acc.z); acc.w = fmaf(w3, v3.w, acc.w);
            acc.x = fmaf(w4, v4.x, acc.x); acc.y = fmaf(w4, v4.y, acc.y);
            acc.z = fmaf(w4, v4.z, acc.z); acc.w = fmaf(w4, v4.w, acc.w);
            acc.x = fmaf(w5, v5.x, acc.x); acc.y = fmaf(w5, v5.y, acc.y);
            acc.z = fmaf(w5, v5.z, acc.z); acc.w = fmaf(w5, v5.w, acc.w);
            acc.x = fmaf(w6, v6.x, acc.x); acc.y = fmaf(w6, v6.y, acc.y);
            acc.z = fmaf(w6, v6.z, acc.z); acc.w = fmaf(w6, v6.w, acc.w);
            acc.x = fmaf(w7, v7.x, acc.x); acc.y = fmaf(w7, v7.y, acc.y);
            acc.z = fmaf(w7, v7.z, acc.z); acc.w = fmaf(w7, v7.w, acc.w);
        }
        for (; n < n1; n += 8) {
            float ww = wlds[n - n0];
            float4 a = v[(size_t)n * 32 + fi];
            acc.x = fmaf(ww, a.x, acc.x);
            acc.y = fmaf(ww, a.y, acc.y);
            acc.z = fmaf(ww, a.z, acc.z);
            acc.w = fmaf(ww, a.w, acc.w);
        }
        part[tid] = acc;
        __syncthreads();
        if (tid < 32) {
            float4 a = part[tid];
            #pragma unroll
            for (int gg = 1; gg < 8; ++gg) {
                float4 b = part[gg * 32 + tid];
                a.x += b.x; a.y += b.y; a.z += b.z; a.w += b.w;
            }
            ((float4*)partial)[((size_t)q * CTXB + cb) * 32 + fi] = a;
        }
        if (tid == 0) zpart[(size_t)q * CTXB + cb] = zred[0] + zred[1] + zred[2] + zred[3];
        __syncthreads();   // protect wlds/zred/part reuse next iteration
    }
    grid.sync();

    // ===== Phase D: final reduce (blocks 0..Q-1) =====
    if (bid < Q) {
        const float* p = partial + (size_t)bid * CTXB * FIN;
        const int f = tid & 127, h = tid >> 7;
        float s = 0.f;
        for (int b = h; b < CTXB; b += 2) s += p[(size_t)b * FIN + f];
        red2[tid] = s;
        float z = (tid < CTXB) ? zpart[(size_t)bid * CTXB + tid] : 0.f;
        #pragma unroll
        for (int off = 32; off; off >>= 1) z += __shfl_xor(z, off);
        if ((tid & 63) == 0) zred[tid >> 6] = z;
        __syncthreads();
        if (tid < 128) {
            float Zt = zred[0] + zred[1] + zred[2] + zred[3];
            ctx[bid * FIN + f] = (red2[tid] + red2[tid + 128]) * (1.f / Zt);
        }
    }
}

// ================= fallback: R11's separate kernels =================
__global__ __launch_bounds__(256, 3) void k_xw(const float* __restrict__ query,
                                               const float* __restrict__ W1,
                                               __half* __restrict__ y, int N) {
    __shared__ _Float16 Wlds[8192];
    const int tid = threadIdx.x;
    #pragma unroll
    for (int it = 0; it < 4; ++it) {
        int p = it * 256 + tid;
        int g6 = p >> 6;
        int kk = g6 >> 2, nt = g6 & 3;
        int lane6 = p & 63;
        int lg = lane6 >> 4, lr = lane6 & 15;
        int f = nt * 16 + lr;
        int kbase = kk * 32 + lg * 8;
        f16x8 fr;
        #pragma unroll
        for (int j = 0; j < 8; ++j)
            fr[j] = (_Float16)W1[(kbase + j) * FOUT + f];
        ((f16x8*)Wlds)[p] = fr;
    }
    __syncthreads();

    const int wave = tid >> 6, lane = tid & 63;
    const int lg = lane >> 4, lr = lane & 15;
    const int q = blockIdx.y;
    const int base = blockIdx.x * 128 + wave * 32;
    const float* qb = query + (size_t)q * N * FIN;
    __half* yq = y + (size_t)q * N * FOUT;
    const f16x8* Bp = (const f16x8*)Wlds;

    int n0 = base + lr;       if (n0 >= N) n0 = N - 1;
    int n1 = base + 16 + lr;  if (n1 >= N) n1 = N - 1;
    const float4* r0 = (const float4*)(qb + (size_t)n0 * FIN);
    const float4* r1 = (const float4*)(qb + (size_t)n1 * FIN);

    float4 a0[8], a1[8];
    #pragma unroll
    for (int kk = 0; kk < 4; ++kk) {
        a0[2 * kk]     = r0[kk * 8 + lg * 2];
        a0[2 * kk + 1] = r0[kk * 8 + lg * 2 + 1];
        a1[2 * kk]     = r1[kk * 8 + lg * 2];
        a1[2 * kk + 1] = r1[kk * 8 + lg * 2 + 1];
    }
    f32x4 acc0[4], acc1[4];
    #pragma unroll
    for (int nt = 0; nt < 4; ++nt) { acc0[nt] = (f32x4)0.f; acc1[nt] = (f32x4)0.f; }
    #pragma unroll
    for (int kk = 0; kk < 4; ++kk) {
        f16x8 A0, A1;
        const float* x0 = (const float*)&a0[2 * kk];
        const float* x1 = (const float*)&a1[2 * kk];
        #pragma unroll
        for (int j = 0; j < 8; ++j) { A0[j] = (_Float16)x0[j]; A1[j] = (_Float16)x1[j]; }
        #pragma unroll
        for (int nt = 0; nt < 4; ++nt) {
            f16x8 Bf = Bp[(kk * 4 + nt) * 64 + lane];
            acc0[nt] = __builtin_amdgcn_mfma_f32_16x16x32_f16(A0, Bf, acc0[nt], 0, 0, 0);
            acc1[nt] = __builtin_amdgcn_mfma_f32_16x16x32_f16(A1, Bf, acc1[nt], 0, 0, 0);
        }
    }
    #pragma unroll
    for (int r = 0; r < 4; ++r) {
        int m0 = base + lg * 4 + r;
        int m1 = base + 16 + lg * 4 + r;
        if (m0 < N) {
            #pragma unroll
            for (int nt = 0; nt < 4; ++nt)
                yq[(size_t)m0 * FOUT + nt * 16 + lr] = __float2half(acc0[nt][r]);
        }
        if (m1 < N) {
            #pragma unroll
            for (int nt = 0; nt < 4; ++nt)
                yq[(size_t)m1 * FOUT + nt * 16 + lr] = __float2half(acc1[nt][r]);
        }
    }
}

__global__ __launch_bounds__(256, 4) void k_agg(const __half* __restrict__ y,
                                                const int* __restrict__ edges,
                                                const float* __restrict__ b1,
                                                const float* __restrict__ W2,
                                                float* __restrict__ s1, int N) {
    const int tid = threadIdx.x;
    const int wave = tid >> 6, lane = tid & 63;
    const int half = lane >> 5, fl = lane & 31;
    const int q = blockIdx.y;
    const int nA = blockIdx.x * 16 + wave * 2 + half;
    const int nB = nA + 8;
    const int ncA = nA < N ? nA : N - 1;
    const int ncB = nB < N ? nB : N - 1;
    const __half2* y2 = (const __half2*)(y + (size_t)q * N * FOUT);

    const int4* erA = (const int4*)(edges + (size_t)ncA * KN);
    const int4* erB = (const int4*)(edges + (size_t)ncB * KN);
    int4 eaA = erA[0], ebA = erA[1];
    int4 eaB = erB[0], ebB = erB[1];

    __half2 a0 = y2[(size_t)eaA.x * 32 + fl], a1 = y2[(size_t)eaA.y * 32 + fl];
    __half2 a2 = y2[(size_t)eaA.z * 32 + fl], a3 = y2[(size_t)eaA.w * 32 + fl];
    __half2 a4 = y2[(size_t)ebA.x * 32 + fl], a5 = y2[(size_t)ebA.y * 32 + fl];
    __half2 a6 = y2[(size_t)ebA.z * 32 + fl], a7 = y2[(size_t)ebA.w * 32 + fl];
    __half2 c0 = y2[(size_t)eaB.x * 32 + fl], c1 = y2[(size_t)eaB.y * 32 + fl];
    __half2 c2 = y2[(size_t)eaB.z * 32 + fl], c3 = y2[(size_t)eaB.w * 32 + fl];
    __half2 c4 = y2[(size_t)ebB.x * 32 + fl], c5 = y2[(size_t)ebB.y * 32 + fl];
    __half2 c6 = y2[(size_t)ebB.z * 32 + fl], c7 = y2[(size_t)ebB.w * 32 + fl];

    __half2 sA = __hadd2(__hadd2(__hadd2(a0, a1), __hadd2(a2, a3)),
                         __hadd2(__hadd2(a4, a5), __hadd2(a6, a7)));
    __half2 sB = __hadd2(__hadd2(__hadd2(c0, c1), __hadd2(c2, c3)),
                         __hadd2(__hadd2(c4, c5), __hadd2(c6, c7)));
    float2 fA = __half22float2(sA);
    float2 fB = __half22float2(sB);
    float2 bv = *(const float2*)(b1 + fl * 2);
    float2 wv = *(const float2*)(W2 + fl * 2);
    float xA0 = fA.x * 0.125f + bv.x, xA1 = fA.y * 0.125f + bv.y;
    float xB0 = fB.x * 0.125f + bv.x, xB1 = fB.y * 0.125f + bv.y;
    float eA0 = __expf(-2.f * fabsf(xA0)), eA1 = __expf(-2.f * fabsf(xA1));
    float eB0 = __expf(-2.f * fabsf(xB0)), eB1 = __expf(-2.f * fabsf(xB1));
    float tA0 = copysignf(__fdividef(1.f - eA0, 1.f + eA0), xA0);
    float tA1 = copysignf(__fdividef(1.f - eA1, 1.f + eA1), xA1);
    float tB0 = copysignf(__fdividef(1.f - eB0, 1.f + eB0), xB0);
    float tB1 = copysignf(__fdividef(1.f - eB1, 1.f + eB1), xB1);
    float pA = tA0 * wv.x + tA1 * wv.y;
    float pB = tB0 * wv.x + tB1 * wv.y;
    #pragma unroll
    for (int off = 16; off; off >>= 1) {
        pA += __shfl_xor(pA, off);
        pB += __shfl_xor(pB, off);
    }
    if (fl == 0) {
        float* s1q = s1 + (size_t)q * N;
        if (nA < N) s1q[nA] = pA;
        if (nB < N) s1q[nB] = pB;
    }
}

__global__ __launch_bounds__(256, 4) void k_ctx(const float* __restrict__ values,
                                                const float* __restrict__ s1,
                                                const int* __restrict__ edges,
                                                const float* __restrict__ b2,
                                                float* __restrict__ score,
                                                float* __restrict__ partial,
                                                float* __restrict__ zpart, int N) {
    const int q = blockIdx.y, cb = blockIdx.x;
    const int tid = threadIdx.x;
    const int n0 = cb * CHUNK, n1 = min(n0 + CHUNK, N);
    const int cnt = n1 - n0;
    __shared__ float wlds[256];
    __shared__ float zred[4];
    const float* s1q = s1 + (size_t)q * N;
    const float b2v = b2[0];

    float zp = 0.f;
    if (tid < cnt) {
        int n = n0 + tid;
        float acc = 0.f;
        #pragma unroll
        for (int k = 0; k < KN; ++k) acc += s1q[edges[(size_t)n * KN + k]];
        float sc = acc * 0.125f + b2v;
        score[(size_t)q * N + n] = sc;
        float ex = __expf(sc);
        wlds[tid] = ex;
        zp = ex;
    }
    float z = zp;
    #pragma unroll
    for (int off = 32; off; off >>= 1) z += __shfl_xor(z, off);
    if ((tid & 63) == 0) zred[tid >> 6] = z;
    __syncthreads();

    const int fi = tid & 31, g = tid >> 5;
    const float4* v = (const float4*)(values + (size_t)q * N * FIN);
    float4 acc = make_float4(0.f, 0.f, 0.f, 0.f);
    int n = n0 + g;
    for (; n + 56 < n1; n += 64) {
        int l = n - n0;
        float w0 = wlds[l],      w1 = wlds[l + 8],  w2 = wlds[l + 16], w3 = wlds[l + 24];
        float w4 = wlds[l + 32], w5 = wlds[l + 40], w6 = wlds[l + 48], w7 = wlds[l + 56];
        float4 v0 = v[(size_t)n * 32 + fi];
        float4 v1 = v[(size_t)(n + 8) * 32 + fi];
        float4 v2 = v[(size_t)(n + 16) * 32 + fi];
        float4 v3 = v[(size_t)(n + 24) * 32 + fi];
        float4 v4 = v[(size_t)(n + 32) * 32 + fi];
        float4 v5 = v[(size_t)(n + 40) * 32 + fi];
        float4 v6 = v[(size_t)(n + 48) * 32 + fi];
        float4 v7 = v[(size_t)(n + 56) * 32 + fi];
        acc.x = fmaf(w0, v0.x, acc.x); acc.y = fmaf(w0, v0.y, acc.y);
        acc.z = fmaf(w0, v0.z, acc.z); acc.w = fmaf(w0, v0.w, acc.w);
        acc.x = fmaf(w1, v1.x, acc.x); acc.y = fmaf(w1, v1.y, acc.y);
        acc.z = fmaf(w1, v1.z, acc.z); acc.w = fmaf(w1, v1.w, acc.w);
        acc.x = fmaf(w2, v2.x, acc.x); acc.y = fmaf(w2, v2.y, acc.y);
        acc.z = fmaf(w2, v2.z, acc.z); acc.w = fmaf(w2, v2.w, acc.w);
        acc.x = fmaf(w3, v3.x, acc.x); acc.y = fmaf(w3, v3.y, acc.y);
        acc.z = fmaf(w3, v3.z, acc.z); acc.w = fmaf(w3, v3.w, acc.w);
        acc.x = fmaf(w4, v4.x, acc.x); acc.y = fmaf(w4, v4.y, acc.y);
        acc.z = fmaf(w4, v4.z, acc.z); acc.w = fmaf(w4, v4.w, acc.w);
        acc.x = fmaf(w5, v5.x, acc.x); acc.y = fmaf(w5, v5.y, acc.y);
        acc.z = fmaf(w5, v5.z, acc.z); acc.w = fmaf(w5, v5.w, acc.w);
        acc.x = fmaf(w6, v6.x, acc.x); acc.y = fmaf(w6, v6.y, acc.y);
        acc.z = fmaf(w6, v6.z, acc.z); acc.w = fmaf(w6, v6.w, acc.w);
        acc.x = fmaf(w7, v7.x, acc.x); acc.y = fmaf(w7, v7.y, acc.y);
        acc.z = fmaf(w7, v7.z, acc.z); acc.w = fmaf(w7, v7.w, acc.w);
    }
    for (; n < n1; n += 8) {
        float ww = wlds[n - n0];
        float4 a = v[(size_t)n * 32 + fi];
        acc.x = fmaf(ww, a.x, acc.x);
        acc.y = fmaf(ww, a.y, acc.y);
        acc.z = fmaf(ww, a.z, acc.z);
        acc.w = fmaf(ww, a.w, acc.w);
    }
    __shared__ float4 part[256];
    part[tid] = acc;
    __syncthreads();
    if (tid < 32) {
        float4 a = part[tid];
        #pragma unroll
        for (int gg = 1; gg < 8; ++gg) {
            float4 b = part[gg * 32 + tid];
            a.x += b.x; a.y += b.y; a.z += b.z; a.w += b.w;
        }
        ((float4*)partial)[((size_t)q * CTXB + cb) * 32 + fi] = a;
    }
    if (tid == 0) zpart[(size_t)q * CTXB + cb] = zred[0] + zred[1] + zred[2] + zred[3];
}

__global__ __launch_bounds__(512) void k_final(const float* __restrict__ partial,
                                               const float* __restrict__ zpart,
                                               float* __restrict__ ctx) {
    const int q = blockIdx.x;
    const int tid = threadIdx.x;
    const int f = tid & 127, h = tid >> 7;
    const float* p = partial + (size_t)q * CTXB * FIN;
    float s = 0.f;
    for (int b = h; b < CTXB; b += 4) s += p[(size_t)b * FIN + f];
    __shared__ float red[512];
    __shared__ float zred[8];
    red[tid] = s;
    float z = (tid < CTXB) ? zpart[(size_t)q * CTXB + tid] : 0.f;
    #pragma unroll
    for (int off = 32; off; off >>= 1) z += __shfl_xor(z, off);
    if ((tid & 63) == 0) zred[tid >> 6] = z;
    __syncthreads();
    if (tid < 128) {
        float Zt = zred[0] + zred[1] + zred[2] + zred[3] +
                   zred[4] + zred[5] + zred[6] + zred[7];
        float t = red[tid] + red[tid + 128] + red[tid + 256] + red[tid + 384];
        ctx[q * FIN + f] = t * (1.f / Zt);
    }
}

extern "C" void kernel_launch(void* const* d_in, const int* in_sizes, int n_in,
                              void* d_out, int out_size, void* d_ws, size_t ws_size,
                              hipStream_t stream) {
    const float* query  = (const float*)d_in[0];
    const float* values = (const float*)d_in[1];
    const int*   edges  = (const int*)d_in[2];
    const float* W1     = (const float*)d_in[3];
    const float* b1     = (const float*)d_in[4];
    const float* W2     = (const float*)d_in[5];
    const float* b2     = (const float*)d_in[6];

    int N = in_sizes[2] / KN;                 // 50000
    int Q = in_sizes[0] / (N * FIN);          // 4

    float* out   = (float*)d_out;
    float* ctx   = out;                       // [Q,128]
    float* score = out + (size_t)Q * FIN;     // [Q,N]

    char* ws = (char*)d_ws;
    __half* y = (__half*)ws;                                    // [Q,N,64] f16
    size_t off = (size_t)Q * N * FOUT * sizeof(__half);
    float* s1    = (float*)(ws + off);  off += (size_t)Q * N * sizeof(float);
    float* part  = (float*)(ws + off);  off += (size_t)Q * CTXB * FIN * sizeof(float);
    float* zpart = (float*)(ws + off);                          // [Q,CTXB]

    void* args[] = {(void*)&query, (void*)&values, (void*)&edges, (void*)&W1,
                    (void*)&b1, (void*)&W2, (void*)&b2, (void*)&ctx,
                    (void*)&score, (void*)&y, (void*)&s1, (void*)&part,
                    (void*)&zpart, (void*)&N, (void*)&Q};
    hipError_t err = hipLaunchCooperativeKernel((void*)k_mega, dim3(GRID),
                                                dim3(256), args, 0, stream);
    if (err != hipSuccess) {
        // deterministic fallback: R11's 4-kernel pipeline
        dim3 g1((N + 127) / 128, Q);
        k_xw<<<g1, 256, 0, stream>>>(query, W1, y, N);
        dim3 g2((N + 15) / 16, Q);
        k_agg<<<g2, 256, 0, stream>>>(y, edges, b1, W2, s1, N);
        dim3 g3(CTXB, Q);
        k_ctx<<<g3, 256, 0, stream>>>(values, s1, edges, b2, score, part, zpart, N);
        k_final<<<Q, 512, 0, stream>>>(part, zpart, ctx);
    }
}

// Round 15
// 207.341 us; speedup vs baseline: 1.4431x; 1.4431x over previous
//
#include <hip/hip_runtime.h>
#include <hip/hip_fp16.h>
#include <math.h>

// GraphAttention: Q=4, N=50000, K=8, F_IN=128, F_OUT=64
//   y  = query @ W1        (single-pass f16 MFMA; f16 out)
//   s1 = tanh(mean_k y[e]+b1) . W2
//   score = mean_k s1[e] + b2
//   softmax without max-sub (scores bounded ~|2|): w=exp(s)/Z
//   ctx = (sum_n exp(s_n) * values[n]) / Z
// 3 launches: k_xw (query prefetch BEFORE W1 pack; zeroes counters),
// k_agg, k_ctx (fused score+exp+stream + last-block final reduce).

#define FIN 128
#define FOUT 64
#define KN 8
#define CTXB 250            // chunks per q
#define CHUNK 200           // nodes per chunk

typedef _Float16 f16x8 __attribute__((ext_vector_type(8)));
typedef float f32x4 __attribute__((ext_vector_type(4)));

// ---------------- Stage 1: y = query @ W1 (f16 MFMA) ----------------
// Query loads issued FIRST (HBM latency), W1 pack overlaps them, then MFMA.
__global__ __launch_bounds__(256, 3) void k_xw(const float* __restrict__ query,
                                               const float* __restrict__ W1,
                                               __half* __restrict__ y,
                                               int* __restrict__ counter,
                                               int N, int Q) {
    __shared__ _Float16 Wlds[8192];   // [16 frags][64 lanes][8 f16]
    const int tid = threadIdx.x;
    const int wave = tid >> 6, lane = tid & 63;
    const int lg = lane >> 4, lr = lane & 15;
    const int q = blockIdx.y;
    const int base = blockIdx.x * 128 + wave * 32;
    const float* qb = query + (size_t)q * N * FIN;
    __half* yq = y + (size_t)q * N * FOUT;

    if (blockIdx.x == 0 && blockIdx.y == 0 && tid < Q) counter[tid] = 0;

    // ---- issue query loads first (in flight during the pack) ----
    int n0 = base + lr;       if (n0 >= N) n0 = N - 1;
    int n1 = base + 16 + lr;  if (n1 >= N) n1 = N - 1;
    const float4* r0 = (const float4*)(qb + (size_t)n0 * FIN);
    const float4* r1 = (const float4*)(qb + (size_t)n1 * FIN);
    float4 a0[8], a1[8];
    #pragma unroll
    for (int kk = 0; kk < 4; ++kk) {
        a0[2 * kk]     = r0[kk * 8 + lg * 2];
        a0[2 * kk + 1] = r0[kk * 8 + lg * 2 + 1];
        a1[2 * kk]     = r1[kk * 8 + lg * 2];
        a1[2 * kk + 1] = r1[kk * 8 + lg * 2 + 1];
    }

    // ---- pack W1 -> LDS (overlaps pending query loads) ----
    #pragma unroll
    for (int it = 0; it < 4; ++it) {
        int p = it * 256 + tid;        // fragment-row 0..1023
        int g6 = p >> 6;               // kk*4+nt
        int kk = g6 >> 2, nt = g6 & 3;
        int lane6 = p & 63;
        int plg = lane6 >> 4, plr = lane6 & 15;
        int f = nt * 16 + plr;
        int kbase = kk * 32 + plg * 8;
        f16x8 fr;
        #pragma unroll
        for (int j = 0; j < 8; ++j)
            fr[j] = (_Float16)W1[(kbase + j) * FOUT + f];
        ((f16x8*)Wlds)[p] = fr;
    }
    __syncthreads();
    const f16x8* Bp = (const f16x8*)Wlds;

    f32x4 acc0[4], acc1[4];
    #pragma unroll
    for (int nt = 0; nt < 4; ++nt) { acc0[nt] = (f32x4)0.f; acc1[nt] = (f32x4)0.f; }

    #pragma unroll
    for (int kk = 0; kk < 4; ++kk) {
        f16x8 A0, A1;
        const float* x0 = (const float*)&a0[2 * kk];
        const float* x1 = (const float*)&a1[2 * kk];
        #pragma unroll
        for (int j = 0; j < 8; ++j) { A0[j] = (_Float16)x0[j]; A1[j] = (_Float16)x1[j]; }
        #pragma unroll
        for (int nt = 0; nt < 4; ++nt) {
            f16x8 Bf = Bp[(kk * 4 + nt) * 64 + lane];
            acc0[nt] = __builtin_amdgcn_mfma_f32_16x16x32_f16(A0, Bf, acc0[nt], 0, 0, 0);
            acc1[nt] = __builtin_amdgcn_mfma_f32_16x16x32_f16(A1, Bf, acc1[nt], 0, 0, 0);
        }
    }
    #pragma unroll
    for (int r = 0; r < 4; ++r) {
        int m0 = base + lg * 4 + r;
        int m1 = base + 16 + lg * 4 + r;
        if (m0 < N) {
            #pragma unroll
            for (int nt = 0; nt < 4; ++nt)
                yq[(size_t)m0 * FOUT + nt * 16 + lr] = __float2half(acc0[nt][r]);
        }
        if (m1 < N) {
            #pragma unroll
            for (int nt = 0; nt < 4; ++nt)
                yq[(size_t)m1 * FOUT + nt * 16 + lr] = __float2half(acc1[nt][r]);
        }
    }
}

// ---------------- Stage 2: s1 = tanh(mean_k y[e]+b1).W2 ----------------
__global__ __launch_bounds__(256, 4) void k_agg(const __half* __restrict__ y,
                                                const int* __restrict__ edges,
                                                const float* __restrict__ b1,
                                                const float* __restrict__ W2,
                                                float* __restrict__ s1, int N) {
    const int tid = threadIdx.x;
    const int wave = tid >> 6, lane = tid & 63;
    const int half = lane >> 5, fl = lane & 31;
    const int q = blockIdx.y;
    const int nA = blockIdx.x * 16 + wave * 2 + half;
    const int nB = nA + 8;
    const int ncA = nA < N ? nA : N - 1;
    const int ncB = nB < N ? nB : N - 1;
    const __half2* y2 = (const __half2*)(y + (size_t)q * N * FOUT);

    const int4* erA = (const int4*)(edges + (size_t)ncA * KN);
    const int4* erB = (const int4*)(edges + (size_t)ncB * KN);
    int4 eaA = erA[0], ebA = erA[1];
    int4 eaB = erB[0], ebB = erB[1];

    __half2 a0 = y2[(size_t)eaA.x * 32 + fl], a1 = y2[(size_t)eaA.y * 32 + fl];
    __half2 a2 = y2[(size_t)eaA.z * 32 + fl], a3 = y2[(size_t)eaA.w * 32 + fl];
    __half2 a4 = y2[(size_t)ebA.x * 32 + fl], a5 = y2[(size_t)ebA.y * 32 + fl];
    __half2 a6 = y2[(size_t)ebA.z * 32 + fl], a7 = y2[(size_t)ebA.w * 32 + fl];
    __half2 c0 = y2[(size_t)eaB.x * 32 + fl], c1 = y2[(size_t)eaB.y * 32 + fl];
    __half2 c2 = y2[(size_t)eaB.z * 32 + fl], c3 = y2[(size_t)eaB.w * 32 + fl];
    __half2 c4 = y2[(size_t)ebB.x * 32 + fl], c5 = y2[(size_t)ebB.y * 32 + fl];
    __half2 c6 = y2[(size_t)ebB.z * 32 + fl], c7 = y2[(size_t)ebB.w * 32 + fl];

    __half2 sA = __hadd2(__hadd2(__hadd2(a0, a1), __hadd2(a2, a3)),
                         __hadd2(__hadd2(a4, a5), __hadd2(a6, a7)));
    __half2 sB = __hadd2(__hadd2(__hadd2(c0, c1), __hadd2(c2, c3)),
                         __hadd2(__hadd2(c4, c5), __hadd2(c6, c7)));
    float2 fA = __half22float2(sA);
    float2 fB = __half22float2(sB);

    float2 bv = *(const float2*)(b1 + fl * 2);
    float2 wv = *(const float2*)(W2 + fl * 2);
    float xA0 = fA.x * 0.125f + bv.x, xA1 = fA.y * 0.125f + bv.y;
    float xB0 = fB.x * 0.125f + bv.x, xB1 = fB.y * 0.125f + bv.y;
    float eA0 = __expf(-2.f * fabsf(xA0)), eA1 = __expf(-2.f * fabsf(xA1));
    float eB0 = __expf(-2.f * fabsf(xB0)), eB1 = __expf(-2.f * fabsf(xB1));
    float tA0 = copysignf(__fdividef(1.f - eA0, 1.f + eA0), xA0);
    float tA1 = copysignf(__fdividef(1.f - eA1, 1.f + eA1), xA1);
    float tB0 = copysignf(__fdividef(1.f - eB0, 1.f + eB0), xB0);
    float tB1 = copysignf(__fdividef(1.f - eB1, 1.f + eB1), xB1);
    float pA = tA0 * wv.x + tA1 * wv.y;
    float pB = tB0 * wv.x + tB1 * wv.y;
    #pragma unroll
    for (int off = 16; off; off >>= 1) {
        pA += __shfl_xor(pA, off);
        pB += __shfl_xor(pB, off);
    }
    if (fl == 0) {
        float* s1q = s1 + (size_t)q * N;
        if (nA < N) s1q[nA] = pA;
        if (nB < N) s1q[nB] = pB;
    }
}

// ---------------- Stage 3: score+exp+Z + weighted values + last-block final ----------------
__global__ __launch_bounds__(256, 4) void k_ctx(const float* __restrict__ values,
                                                const float* __restrict__ s1,
                                                const int* __restrict__ edges,
                                                const float* __restrict__ b2,
                                                float* __restrict__ score,
                                                float* __restrict__ partial,
                                                float* __restrict__ zpart,
                                                int* __restrict__ counter,
                                                float* __restrict__ ctx, int N) {
    const int q = blockIdx.y, cb = blockIdx.x;
    const int tid = threadIdx.x;
    const int n0 = cb * CHUNK, n1 = min(n0 + CHUNK, N);
    const int cnt = n1 - n0;
    __shared__ float wlds[256];
    __shared__ float zred[4];
    __shared__ float4 part[256];
    __shared__ float red2[256];
    __shared__ int isLast;
    const float* s1q = s1 + (size_t)q * N;
    const float b2v = b2[0];

    // phase 1: scores + exp for this chunk
    float zp = 0.f;
    if (tid < cnt) {
        int n = n0 + tid;
        float acc = 0.f;
        #pragma unroll
        for (int k = 0; k < KN; ++k) acc += s1q[edges[(size_t)n * KN + k]];
        float sc = acc * 0.125f + b2v;
        score[(size_t)q * N + n] = sc;
        float ex = __expf(sc);
        wlds[tid] = ex;
        zp = ex;
    }
    float z = zp;
    #pragma unroll
    for (int off = 32; off; off >>= 1) z += __shfl_xor(z, off);
    if ((tid & 63) == 0) zred[tid >> 6] = z;
    __syncthreads();

    // phase 2: weighted values stream
    const int fi = tid & 31, g = tid >> 5;
    const float4* v = (const float4*)(values + (size_t)q * N * FIN);
    float4 acc = make_float4(0.f, 0.f, 0.f, 0.f);
    int n = n0 + g;
    for (; n + 56 < n1; n += 64) {
        int l = n - n0;
        float w0 = wlds[l],      w1 = wlds[l + 8],  w2 = wlds[l + 16], w3 = wlds[l + 24];
        float w4 = wlds[l + 32], w5 = wlds[l + 40], w6 = wlds[l + 48], w7 = wlds[l + 56];
        float4 v0 = v[(size_t)n * 32 + fi];
        float4 v1 = v[(size_t)(n + 8) * 32 + fi];
        float4 v2 = v[(size_t)(n + 16) * 32 + fi];
        float4 v3 = v[(size_t)(n + 24) * 32 + fi];
        float4 v4 = v[(size_t)(n + 32) * 32 + fi];
        float4 v5 = v[(size_t)(n + 40) * 32 + fi];
        float4 v6 = v[(size_t)(n + 48) * 32 + fi];
        float4 v7 = v[(size_t)(n + 56) * 32 + fi];
        acc.x = fmaf(w0, v0.x, acc.x); acc.y = fmaf(w0, v0.y, acc.y);
        acc.z = fmaf(w0, v0.z, acc.z); acc.w = fmaf(w0, v0.w, acc.w);
        acc.x = fmaf(w1, v1.x, acc.x); acc.y = fmaf(w1, v1.y, acc.y);
        acc.z = fmaf(w1, v1.z, acc.z); acc.w = fmaf(w1, v1.w, acc.w);
        acc.x = fmaf(w2, v2.x, acc.x); acc.y = fmaf(w2, v2.y, acc.y);
        acc.z = fmaf(w2, v2.z, acc.z); acc.w = fmaf(w2, v2.w, acc.w);
        acc.x = fmaf(w3, v3.x, acc.x); acc.y = fmaf(w3, v3.y, acc.y);
        acc.z = fmaf(w3, v3.z, acc.z); acc.w = fmaf(w3, v3.w, acc.w);
        acc.x = fmaf(w4, v4.x, acc.x); acc.y = fmaf(w4, v4.y, acc.y);
        acc.z = fmaf(w4, v4.z, acc.z); acc.w = fmaf(w4, v4.w, acc.w);
        acc.x = fmaf(w5, v5.x, acc.x); acc.y = fmaf(w5, v5.y, acc.y);
        acc.z = fmaf(w5, v5.z, acc.z); acc.w = fmaf(w5, v5.w, acc.w);
        acc.x = fmaf(w6, v6.x, acc.x); acc.y = fmaf(w6, v6.y, acc.y);
        acc.z = fmaf(w6, v6.z, acc.z); acc.w = fmaf(w6, v6.w, acc.w);
        acc.x = fmaf(w7, v7.x, acc.x); acc.y = fmaf(w7, v7.y, acc.y);
        acc.z = fmaf(w7, v7.z, acc.z); acc.w = fmaf(w7, v7.w, acc.w);
    }
    for (; n < n1; n += 8) {
        float ww = wlds[n - n0];
        float4 a = v[(size_t)n * 32 + fi];
        acc.x = fmaf(ww, a.x, acc.x);
        acc.y = fmaf(ww, a.y, acc.y);
        acc.z = fmaf(ww, a.z, acc.z);
        acc.w = fmaf(ww, a.w, acc.w);
    }
    part[tid] = acc;
    __syncthreads();
    if (tid < 32) {
        float4 a = part[tid];
        #pragma unroll
        for (int gg = 1; gg < 8; ++gg) {
            float4 b = part[gg * 32 + tid];
            a.x += b.x; a.y += b.y; a.z += b.z; a.w += b.w;
        }
        ((float4*)partial)[((size_t)q * CTXB + cb) * 32 + fi] = a;
    }
    if (tid == 0) zpart[(size_t)q * CTXB + cb] = zred[0] + zred[1] + zred[2] + zred[3];

    // ---- last-block final reduce (replaces k_final) ----
    __threadfence();
    __syncthreads();
    if (tid == 0) {
        int old = atomicAdd(&counter[q], 1);
        isLast = (old == CTXB - 1);
    }
    __syncthreads();
    if (isLast) {
        const float* p = partial + (size_t)q * CTXB * FIN;
        const int f = tid & 127, h = tid >> 7;
        float s = 0.f;
        for (int b = h; b < CTXB; b += 2) s += p[(size_t)b * FIN + f];
        red2[tid] = s;
        float zz = (tid < CTXB) ? zpart[(size_t)q * CTXB + tid] : 0.f;
        #pragma unroll
        for (int off = 32; off; off >>= 1) zz += __shfl_xor(zz, off);
        if ((tid & 63) == 0) zred[tid >> 6] = zz;
        __syncthreads();
        if (tid < 128) {
            float Zt = zred[0] + zred[1] + zred[2] + zred[3];
            ctx[q * FIN + f] = (red2[tid] + red2[tid + 128]) * (1.f / Zt);
        }
    }
}

extern "C" void kernel_launch(void* const* d_in, const int* in_sizes, int n_in,
                              void* d_out, int out_size, void* d_ws, size_t ws_size,
                              hipStream_t stream) {
    const float* query  = (const float*)d_in[0];
    const float* values = (const float*)d_in[1];
    const int*   edges  = (const int*)d_in[2];
    const float* W1     = (const float*)d_in[3];
    const float* b1     = (const float*)d_in[4];
    const float* W2     = (const float*)d_in[5];
    const float* b2     = (const float*)d_in[6];

    int N = in_sizes[2] / KN;                 // 50000
    int Q = in_sizes[0] / (N * FIN);          // 4

    float* out   = (float*)d_out;
    float* ctx   = out;                       // [Q,128]
    float* score = out + (size_t)Q * FIN;     // [Q,N]

    char* ws = (char*)d_ws;
    __half* y = (__half*)ws;                                    // [Q,N,64] f16
    size_t off = (size_t)Q * N * FOUT * sizeof(__half);
    float* s1    = (float*)(ws + off);  off += (size_t)Q * N * sizeof(float);
    float* part  = (float*)(ws + off);  off += (size_t)Q * CTXB * FIN * sizeof(float);
    float* zpart = (float*)(ws + off);  off += (size_t)Q * CTXB * sizeof(float);
    int* counter = (int*)(ws + off);                            // [Q]

    dim3 g1((N + 127) / 128, Q);
    k_xw<<<g1, 256, 0, stream>>>(query, W1, y, counter, N, Q);
    dim3 g2((N + 15) / 16, Q);
    k_agg<<<g2, 256, 0, stream>>>(y, edges, b1, W2, s1, N);
    dim3 g3(CTXB, Q);
    k_ctx<<<g3, 256, 0, stream>>>(values, s1, edges, b2, score, part, zpart,
                                  counter, ctx, N);
}

// Round 16
// 86.608 us; speedup vs baseline: 3.4547x; 2.3940x over previous
//
#include <hip/hip_runtime.h>
#include <hip/hip_fp16.h>
#include <math.h>

// GraphAttention: Q=4, N=50000, K=8, F_IN=128, F_OUT=64
//   y  = query @ W1        (single-pass f16 MFMA; f16 out)
//   s1 = tanh(mean_k y[e]+b1) . W2
//   score = mean_k s1[e] + b2
//   softmax without max-sub (scores bounded ~|2|): w=exp(s)/Z
//   ctx = (sum_n exp(s_n) * values[n]) / Z
// 4 launches (R11 structure; R14's threadfence last-block reduce REVERTED —
// device-scope fences per block serialize cross-XCD traffic, 2.4x regression).
// Only retained change: k_xw issues query loads BEFORE the W1 pack.

#define FIN 128
#define FOUT 64
#define KN 8
#define CTXB 250            // chunks per q
#define CHUNK 200           // nodes per chunk

typedef _Float16 f16x8 __attribute__((ext_vector_type(8)));
typedef float f32x4 __attribute__((ext_vector_type(4)));

// ---------------- Stage 1: y = query @ W1 (f16 MFMA) ----------------
__global__ __launch_bounds__(256, 3) void k_xw(const float* __restrict__ query,
                                               const float* __restrict__ W1,
                                               __half* __restrict__ y, int N) {
    __shared__ _Float16 Wlds[8192];   // [16 frags][64 lanes][8 f16]
    const int tid = threadIdx.x;
    const int wave = tid >> 6, lane = tid & 63;
    const int lg = lane >> 4, lr = lane & 15;
    const int q = blockIdx.y;
    const int base = blockIdx.x * 128 + wave * 32;
    const float* qb = query + (size_t)q * N * FIN;
    __half* yq = y + (size_t)q * N * FOUT;

    // ---- issue query loads first (in flight during the pack) ----
    int n0 = base + lr;       if (n0 >= N) n0 = N - 1;
    int n1 = base + 16 + lr;  if (n1 >= N) n1 = N - 1;
    const float4* r0 = (const float4*)(qb + (size_t)n0 * FIN);
    const float4* r1 = (const float4*)(qb + (size_t)n1 * FIN);
    float4 a0[8], a1[8];
    #pragma unroll
    for (int kk = 0; kk < 4; ++kk) {
        a0[2 * kk]     = r0[kk * 8 + lg * 2];
        a0[2 * kk + 1] = r0[kk * 8 + lg * 2 + 1];
        a1[2 * kk]     = r1[kk * 8 + lg * 2];
        a1[2 * kk + 1] = r1[kk * 8 + lg * 2 + 1];
    }

    // ---- pack W1 -> LDS (overlaps pending query loads) ----
    #pragma unroll
    for (int it = 0; it < 4; ++it) {
        int p = it * 256 + tid;        // fragment-row 0..1023
        int g6 = p >> 6;               // kk*4+nt
        int kk = g6 >> 2, nt = g6 & 3;
        int lane6 = p & 63;
        int plg = lane6 >> 4, plr = lane6 & 15;
        int f = nt * 16 + plr;
        int kbase = kk * 32 + plg * 8;
        f16x8 fr;
        #pragma unroll
        for (int j = 0; j < 8; ++j)
            fr[j] = (_Float16)W1[(kbase + j) * FOUT + f];
        ((f16x8*)Wlds)[p] = fr;
    }
    __syncthreads();
    const f16x8* Bp = (const f16x8*)Wlds;

    f32x4 acc0[4], acc1[4];
    #pragma unroll
    for (int nt = 0; nt < 4; ++nt) { acc0[nt] = (f32x4)0.f; acc1[nt] = (f32x4)0.f; }

    #pragma unroll
    for (int kk = 0; kk < 4; ++kk) {
        f16x8 A0, A1;
        const float* x0 = (const float*)&a0[2 * kk];
        const float* x1 = (const float*)&a1[2 * kk];
        #pragma unroll
        for (int j = 0; j < 8; ++j) { A0[j] = (_Float16)x0[j]; A1[j] = (_Float16)x1[j]; }
        #pragma unroll
        for (int nt = 0; nt < 4; ++nt) {
            f16x8 Bf = Bp[(kk * 4 + nt) * 64 + lane];
            acc0[nt] = __builtin_amdgcn_mfma_f32_16x16x32_f16(A0, Bf, acc0[nt], 0, 0, 0);
            acc1[nt] = __builtin_amdgcn_mfma_f32_16x16x32_f16(A1, Bf, acc1[nt], 0, 0, 0);
        }
    }
    #pragma unroll
    for (int r = 0; r < 4; ++r) {
        int m0 = base + lg * 4 + r;
        int m1 = base + 16 + lg * 4 + r;
        if (m0 < N) {
            #pragma unroll
            for (int nt = 0; nt < 4; ++nt)
                yq[(size_t)m0 * FOUT + nt * 16 + lr] = __float2half(acc0[nt][r]);
        }
        if (m1 < N) {
            #pragma unroll
            for (int nt = 0; nt < 4; ++nt)
                yq[(size_t)m1 * FOUT + nt * 16 + lr] = __float2half(acc1[nt][r]);
        }
    }
}

// ---------------- Stage 2: s1 = tanh(mean_k y[e]+b1).W2 ----------------
__global__ __launch_bounds__(256, 4) void k_agg(const __half* __restrict__ y,
                                                const int* __restrict__ edges,
                                                const float* __restrict__ b1,
                                                const float* __restrict__ W2,
                                                float* __restrict__ s1, int N) {
    const int tid = threadIdx.x;
    const int wave = tid >> 6, lane = tid & 63;
    const int half = lane >> 5, fl = lane & 31;
    const int q = blockIdx.y;
    const int nA = blockIdx.x * 16 + wave * 2 + half;
    const int nB = nA + 8;
    const int ncA = nA < N ? nA : N - 1;
    const int ncB = nB < N ? nB : N - 1;
    const __half2* y2 = (const __half2*)(y + (size_t)q * N * FOUT);

    const int4* erA = (const int4*)(edges + (size_t)ncA * KN);
    const int4* erB = (const int4*)(edges + (size_t)ncB * KN);
    int4 eaA = erA[0], ebA = erA[1];
    int4 eaB = erB[0], ebB = erB[1];

    __half2 a0 = y2[(size_t)eaA.x * 32 + fl], a1 = y2[(size_t)eaA.y * 32 + fl];
    __half2 a2 = y2[(size_t)eaA.z * 32 + fl], a3 = y2[(size_t)eaA.w * 32 + fl];
    __half2 a4 = y2[(size_t)ebA.x * 32 + fl], a5 = y2[(size_t)ebA.y * 32 + fl];
    __half2 a6 = y2[(size_t)ebA.z * 32 + fl], a7 = y2[(size_t)ebA.w * 32 + fl];
    __half2 c0 = y2[(size_t)eaB.x * 32 + fl], c1 = y2[(size_t)eaB.y * 32 + fl];
    __half2 c2 = y2[(size_t)eaB.z * 32 + fl], c3 = y2[(size_t)eaB.w * 32 + fl];
    __half2 c4 = y2[(size_t)ebB.x * 32 + fl], c5 = y2[(size_t)ebB.y * 32 + fl];
    __half2 c6 = y2[(size_t)ebB.z * 32 + fl], c7 = y2[(size_t)ebB.w * 32 + fl];

    __half2 sA = __hadd2(__hadd2(__hadd2(a0, a1), __hadd2(a2, a3)),
                         __hadd2(__hadd2(a4, a5), __hadd2(a6, a7)));
    __half2 sB = __hadd2(__hadd2(__hadd2(c0, c1), __hadd2(c2, c3)),
                         __hadd2(__hadd2(c4, c5), __hadd2(c6, c7)));
    float2 fA = __half22float2(sA);
    float2 fB = __half22float2(sB);

    float2 bv = *(const float2*)(b1 + fl * 2);
    float2 wv = *(const float2*)(W2 + fl * 2);
    float xA0 = fA.x * 0.125f + bv.x, xA1 = fA.y * 0.125f + bv.y;
    float xB0 = fB.x * 0.125f + bv.x, xB1 = fB.y * 0.125f + bv.y;
    float eA0 = __expf(-2.f * fabsf(xA0)), eA1 = __expf(-2.f * fabsf(xA1));
    float eB0 = __expf(-2.f * fabsf(xB0)), eB1 = __expf(-2.f * fabsf(xB1));
    float tA0 = copysignf(__fdividef(1.f - eA0, 1.f + eA0), xA0);
    float tA1 = copysignf(__fdividef(1.f - eA1, 1.f + eA1), xA1);
    float tB0 = copysignf(__fdividef(1.f - eB0, 1.f + eB0), xB0);
    float tB1 = copysignf(__fdividef(1.f - eB1, 1.f + eB1), xB1);
    float pA = tA0 * wv.x + tA1 * wv.y;
    float pB = tB0 * wv.x + tB1 * wv.y;
    #pragma unroll
    for (int off = 16; off; off >>= 1) {
        pA += __shfl_xor(pA, off);
        pB += __shfl_xor(pB, off);
    }
    if (fl == 0) {
        float* s1q = s1 + (size_t)q * N;
        if (nA < N) s1q[nA] = pA;
        if (nB < N) s1q[nB] = pB;
    }
}

// ---------------- Stage 3 (fused): score + exp + Z-partial + weighted values ----------------
__global__ __launch_bounds__(256, 4) void k_ctx(const float* __restrict__ values,
                                                const float* __restrict__ s1,
                                                const int* __restrict__ edges,
                                                const float* __restrict__ b2,
                                                float* __restrict__ score,
                                                float* __restrict__ partial,
                                                float* __restrict__ zpart, int N) {
    const int q = blockIdx.y, cb = blockIdx.x;
    const int tid = threadIdx.x;
    const int n0 = cb * CHUNK, n1 = min(n0 + CHUNK, N);
    const int cnt = n1 - n0;
    __shared__ float wlds[256];
    __shared__ float zred[4];
    const float* s1q = s1 + (size_t)q * N;
    const float b2v = b2[0];

    float zp = 0.f;
    if (tid < cnt) {
        int n = n0 + tid;
        float acc = 0.f;
        #pragma unroll
        for (int k = 0; k < KN; ++k) acc += s1q[edges[(size_t)n * KN + k]];
        float sc = acc * 0.125f + b2v;
        score[(size_t)q * N + n] = sc;
        float ex = __expf(sc);
        wlds[tid] = ex;
        zp = ex;
    }
    float z = zp;
    #pragma unroll
    for (int off = 32; off; off >>= 1) z += __shfl_xor(z, off);
    if ((tid & 63) == 0) zred[tid >> 6] = z;
    __syncthreads();

    const int fi = tid & 31, g = tid >> 5;
    const float4* v = (const float4*)(values + (size_t)q * N * FIN);
    float4 acc = make_float4(0.f, 0.f, 0.f, 0.f);
    int n = n0 + g;
    for (; n + 56 < n1; n += 64) {
        int l = n - n0;
        float w0 = wlds[l],      w1 = wlds[l + 8],  w2 = wlds[l + 16], w3 = wlds[l + 24];
        float w4 = wlds[l + 32], w5 = wlds[l + 40], w6 = wlds[l + 48], w7 = wlds[l + 56];
        float4 v0 = v[(size_t)n * 32 + fi];
        float4 v1 = v[(size_t)(n + 8) * 32 + fi];
        float4 v2 = v[(size_t)(n + 16) * 32 + fi];
        float4 v3 = v[(size_t)(n + 24) * 32 + fi];
        float4 v4 = v[(size_t)(n + 32) * 32 + fi];
        float4 v5 = v[(size_t)(n + 40) * 32 + fi];
        float4 v6 = v[(size_t)(n + 48) * 32 + fi];
        float4 v7 = v[(size_t)(n + 56) * 32 + fi];
        acc.x = fmaf(w0, v0.x, acc.x); acc.y = fmaf(w0, v0.y, acc.y);
        acc.z = fmaf(w0, v0.z, acc.z); acc.w = fmaf(w0, v0.w, acc.w);
        acc.x = fmaf(w1, v1.x, acc.x); acc.y = fmaf(w1, v1.y, acc.y);
        acc.z = fmaf(w1, v1.z, acc.z); acc.w = fmaf(w1, v1.w, acc.w);
        acc.x = fmaf(w2, v2.x, acc.x); acc.y = fmaf(w2, v2.y, acc.y);
        acc.z = fmaf(w2, v2.z, acc.z); acc.w = fmaf(w2, v2.w, acc.w);
        acc.x = fmaf(w3, v3.x, acc.x); acc.y = fmaf(w3, v3.y, acc.y);
        acc.z = fmaf(w3, v3.z, acc.z); acc.w = fmaf(w3, v3.w, acc.w);
        acc.x = fmaf(w4, v4.x, acc.x); acc.y = fmaf(w4, v4.y, acc.y);
        acc.z = fmaf(w4, v4.z, acc.z); acc.w = fmaf(w4, v4.w, acc.w);
        acc.x = fmaf(w5, v5.x, acc.x); acc.y = fmaf(w5, v5.y, acc.y);
        acc.z = fmaf(w5, v5.z, acc.z); acc.w = fmaf(w5, v5.w, acc.w);
        acc.x = fmaf(w6, v6.x, acc.x); acc.y = fmaf(w6, v6.y, acc.y);
        acc.z = fmaf(w6, v6.z, acc.z); acc.w = fmaf(w6, v6.w, acc.w);
        acc.x = fmaf(w7, v7.x, acc.x); acc.y = fmaf(w7, v7.y, acc.y);
        acc.z = fmaf(w7, v7.z, acc.z); acc.w = fmaf(w7, v7.w, acc.w);
    }
    for (; n < n1; n += 8) {
        float ww = wlds[n - n0];
        float4 a = v[(size_t)n * 32 + fi];
        acc.x = fmaf(ww, a.x, acc.x);
        acc.y = fmaf(ww, a.y, acc.y);
        acc.z = fmaf(ww, a.z, acc.z);
        acc.w = fmaf(ww, a.w, acc.w);
    }
    __shared__ float4 part[256];
    part[tid] = acc;
    __syncthreads();
    if (tid < 32) {
        float4 a = part[tid];
        #pragma unroll
        for (int gg = 1; gg < 8; ++gg) {
            float4 b = part[gg * 32 + tid];
            a.x += b.x; a.y += b.y; a.z += b.z; a.w += b.w;
        }
        ((float4*)partial)[((size_t)q * CTXB + cb) * 32 + fi] = a;
    }
    if (tid == 0) zpart[(size_t)q * CTXB + cb] = zred[0] + zred[1] + zred[2] + zred[3];
}

// ---------------- Stage 4: ctx[q,f] = (Σ_cb partial[q,cb,f]) / (Σ_cb zpart[q,cb]) ----------------
__global__ __launch_bounds__(512) void k_final(const float* __restrict__ partial,
                                               const float* __restrict__ zpart,
                                               float* __restrict__ ctx) {
    const int q = blockIdx.x;
    const int tid = threadIdx.x;
    const int f = tid & 127, h = tid >> 7;
    const float* p = partial + (size_t)q * CTXB * FIN;
    float s = 0.f;
    for (int b = h; b < CTXB; b += 4) s += p[(size_t)b * FIN + f];
    __shared__ float red[512];
    __shared__ float zred[8];
    red[tid] = s;
    float z = (tid < CTXB) ? zpart[(size_t)q * CTXB + tid] : 0.f;
    #pragma unroll
    for (int off = 32; off; off >>= 1) z += __shfl_xor(z, off);
    if ((tid & 63) == 0) zred[tid >> 6] = z;
    __syncthreads();
    if (tid < 128) {
        float Zt = zred[0] + zred[1] + zred[2] + zred[3] +
                   zred[4] + zred[5] + zred[6] + zred[7];
        float t = red[tid] + red[tid + 128] + red[tid + 256] + red[tid + 384];
        ctx[q * FIN + f] = t * (1.f / Zt);
    }
}

extern "C" void kernel_launch(void* const* d_in, const int* in_sizes, int n_in,
                              void* d_out, int out_size, void* d_ws, size_t ws_size,
                              hipStream_t stream) {
    const float* query  = (const float*)d_in[0];
    const float* values = (const float*)d_in[1];
    const int*   edges  = (const int*)d_in[2];
    const float* W1     = (const float*)d_in[3];
    const float* b1     = (const float*)d_in[4];
    const float* W2     = (const float*)d_in[5];
    const float* b2     = (const float*)d_in[6];

    int N = in_sizes[2] / KN;                 // 50000
    int Q = in_sizes[0] / (N * FIN);          // 4

    float* out   = (float*)d_out;
    float* ctx   = out;                       // [Q,128]
    float* score = out + (size_t)Q * FIN;     // [Q,N]

    char* ws = (char*)d_ws;
    __half* y = (__half*)ws;                                    // [Q,N,64] f16
    size_t off = (size_t)Q * N * FOUT * sizeof(__half);
    float* s1    = (float*)(ws + off);  off += (size_t)Q * N * sizeof(float);
    float* part  = (float*)(ws + off);  off += (size_t)Q * CTXB * FIN * sizeof(float);
    float* zpart = (float*)(ws + off);                          // [Q,CTXB]

    dim3 g1((N + 127) / 128, Q);
    k_xw<<<g1, 256, 0, stream>>>(query, W1, y, N);
    dim3 g2((N + 15) / 16, Q);
    k_agg<<<g2, 256, 0, stream>>>(y, edges, b1, W2, s1, N);
    dim3 g3(CTXB, Q);
    k_ctx<<<g3, 256, 0, stream>>>(values, s1, edges, b2, score, part, zpart, N);
    k_final<<<Q, 512, 0, stream>>>(part, zpart, ctx);
}

// Round 17
// 85.382 us; speedup vs baseline: 3.5043x; 1.0144x over previous
//
#include <hip/hip_runtime.h>
#include <hip/hip_fp16.h>
#include <math.h>

// GraphAttention: Q=4, N=50000, K=8, F_IN=128, F_OUT=64
//   y  = query @ W1        (single-pass f16 MFMA; f16 out)
//   s1 = tanh(mean_k y[e]+b1) . W2
//   score = mean_k s1[e] + b2
//   softmax without max-sub (scores bounded ~|2|): w=exp(s)/Z
//   ctx = (sum_n exp(s_n) * values[n]) / Z
// 4 launches. This round: k_agg 4 node-chains/wave (32 gathers in flight)
// to probe latency- vs BW-bound on the L3-resident y gathers.

#define FIN 128
#define FOUT 64
#define KN 8
#define CTXB 250            // chunks per q
#define CHUNK 200           // nodes per chunk

typedef _Float16 f16x8 __attribute__((ext_vector_type(8)));
typedef float f32x4 __attribute__((ext_vector_type(4)));

// ---------------- Stage 1: y = query @ W1 (f16 MFMA) ----------------
__global__ __launch_bounds__(256, 3) void k_xw(const float* __restrict__ query,
                                               const float* __restrict__ W1,
                                               __half* __restrict__ y, int N) {
    __shared__ _Float16 Wlds[8192];   // [16 frags][64 lanes][8 f16]
    const int tid = threadIdx.x;
    const int wave = tid >> 6, lane = tid & 63;
    const int lg = lane >> 4, lr = lane & 15;
    const int q = blockIdx.y;
    const int base = blockIdx.x * 128 + wave * 32;
    const float* qb = query + (size_t)q * N * FIN;
    __half* yq = y + (size_t)q * N * FOUT;

    // ---- issue query loads first (in flight during the pack) ----
    int n0 = base + lr;       if (n0 >= N) n0 = N - 1;
    int n1 = base + 16 + lr;  if (n1 >= N) n1 = N - 1;
    const float4* r0 = (const float4*)(qb + (size_t)n0 * FIN);
    const float4* r1 = (const float4*)(qb + (size_t)n1 * FIN);
    float4 a0[8], a1[8];
    #pragma unroll
    for (int kk = 0; kk < 4; ++kk) {
        a0[2 * kk]     = r0[kk * 8 + lg * 2];
        a0[2 * kk + 1] = r0[kk * 8 + lg * 2 + 1];
        a1[2 * kk]     = r1[kk * 8 + lg * 2];
        a1[2 * kk + 1] = r1[kk * 8 + lg * 2 + 1];
    }

    // ---- pack W1 -> LDS (overlaps pending query loads) ----
    #pragma unroll
    for (int it = 0; it < 4; ++it) {
        int p = it * 256 + tid;        // fragment-row 0..1023
        int g6 = p >> 6;               // kk*4+nt
        int kk = g6 >> 2, nt = g6 & 3;
        int lane6 = p & 63;
        int plg = lane6 >> 4, plr = lane6 & 15;
        int f = nt * 16 + plr;
        int kbase = kk * 32 + plg * 8;
        f16x8 fr;
        #pragma unroll
        for (int j = 0; j < 8; ++j)
            fr[j] = (_Float16)W1[(kbase + j) * FOUT + f];
        ((f16x8*)Wlds)[p] = fr;
    }
    __syncthreads();
    const f16x8* Bp = (const f16x8*)Wlds;

    f32x4 acc0[4], acc1[4];
    #pragma unroll
    for (int nt = 0; nt < 4; ++nt) { acc0[nt] = (f32x4)0.f; acc1[nt] = (f32x4)0.f; }

    #pragma unroll
    for (int kk = 0; kk < 4; ++kk) {
        f16x8 A0, A1;
        const float* x0 = (const float*)&a0[2 * kk];
        const float* x1 = (const float*)&a1[2 * kk];
        #pragma unroll
        for (int j = 0; j < 8; ++j) { A0[j] = (_Float16)x0[j]; A1[j] = (_Float16)x1[j]; }
        #pragma unroll
        for (int nt = 0; nt < 4; ++nt) {
            f16x8 Bf = Bp[(kk * 4 + nt) * 64 + lane];
            acc0[nt] = __builtin_amdgcn_mfma_f32_16x16x32_f16(A0, Bf, acc0[nt], 0, 0, 0);
            acc1[nt] = __builtin_amdgcn_mfma_f32_16x16x32_f16(A1, Bf, acc1[nt], 0, 0, 0);
        }
    }
    #pragma unroll
    for (int r = 0; r < 4; ++r) {
        int m0 = base + lg * 4 + r;
        int m1 = base + 16 + lg * 4 + r;
        if (m0 < N) {
            #pragma unroll
            for (int nt = 0; nt < 4; ++nt)
                yq[(size_t)m0 * FOUT + nt * 16 + lr] = __float2half(acc0[nt][r]);
        }
        if (m1 < N) {
            #pragma unroll
            for (int nt = 0; nt < 4; ++nt)
                yq[(size_t)m1 * FOUT + nt * 16 + lr] = __float2half(acc1[nt][r]);
        }
    }
}

// ---------------- Stage 2: s1 = tanh(mean_k y[e]+b1).W2 ----------------
// 4 node-chains per wave-half pair: block covers 32 nodes; 32 independent
// gathers in flight per wave (latency probe vs R15's 16).
__global__ __launch_bounds__(256, 4) void k_agg(const __half* __restrict__ y,
                                                const int* __restrict__ edges,
                                                const float* __restrict__ b1,
                                                const float* __restrict__ W2,
                                                float* __restrict__ s1, int N) {
    const int tid = threadIdx.x;
    const int wave = tid >> 6, lane = tid & 63;
    const int half = lane >> 5, fl = lane & 31;
    const int q = blockIdx.y;
    const int base = blockIdx.x * 32 + wave * 8 + half;   // chains at base+2c
    const __half2* y2 = (const __half2*)(y + (size_t)q * N * FOUT);

    int n[4], nc[4];
    #pragma unroll
    for (int c = 0; c < 4; ++c) {
        n[c] = base + 2 * c;
        nc[c] = n[c] < N ? n[c] : N - 1;
    }
    int4 ea[4], eb[4];
    #pragma unroll
    for (int c = 0; c < 4; ++c) {
        const int4* er = (const int4*)(edges + (size_t)nc[c] * KN);
        ea[c] = er[0];
        eb[c] = er[1];
    }
    __half2 v[4][8];
    #pragma unroll
    for (int c = 0; c < 4; ++c) {
        v[c][0] = y2[(size_t)ea[c].x * 32 + fl];
        v[c][1] = y2[(size_t)ea[c].y * 32 + fl];
        v[c][2] = y2[(size_t)ea[c].z * 32 + fl];
        v[c][3] = y2[(size_t)ea[c].w * 32 + fl];
        v[c][4] = y2[(size_t)eb[c].x * 32 + fl];
        v[c][5] = y2[(size_t)eb[c].y * 32 + fl];
        v[c][6] = y2[(size_t)eb[c].z * 32 + fl];
        v[c][7] = y2[(size_t)eb[c].w * 32 + fl];
    }

    float2 bv = *(const float2*)(b1 + fl * 2);
    float2 wv = *(const float2*)(W2 + fl * 2);

    float p[4];
    #pragma unroll
    for (int c = 0; c < 4; ++c) {
        __half2 s01 = __hadd2(v[c][0], v[c][1]), s23 = __hadd2(v[c][2], v[c][3]);
        __half2 s45 = __hadd2(v[c][4], v[c][5]), s67 = __hadd2(v[c][6], v[c][7]);
        __half2 sum = __hadd2(__hadd2(s01, s23), __hadd2(s45, s67));
        float2 sf = __half22float2(sum);
        float x0 = sf.x * 0.125f + bv.x;
        float x1 = sf.y * 0.125f + bv.y;
        float e0 = __expf(-2.f * fabsf(x0)), e1 = __expf(-2.f * fabsf(x1));
        float t0 = copysignf(__fdividef(1.f - e0, 1.f + e0), x0);
        float t1 = copysignf(__fdividef(1.f - e1, 1.f + e1), x1);
        p[c] = t0 * wv.x + t1 * wv.y;
    }
    #pragma unroll
    for (int off = 16; off; off >>= 1) {
        p[0] += __shfl_xor(p[0], off);
        p[1] += __shfl_xor(p[1], off);
        p[2] += __shfl_xor(p[2], off);
        p[3] += __shfl_xor(p[3], off);
    }
    if (fl == 0) {
        float* s1q = s1 + (size_t)q * N;
        #pragma unroll
        for (int c = 0; c < 4; ++c)
            if (n[c] < N) s1q[n[c]] = p[c];
    }
}

// ---------------- Stage 3 (fused): score + exp + Z-partial + weighted values ----------------
__global__ __launch_bounds__(256, 4) void k_ctx(const float* __restrict__ values,
                                                const float* __restrict__ s1,
                                                const int* __restrict__ edges,
                                                const float* __restrict__ b2,
                                                float* __restrict__ score,
                                                float* __restrict__ partial,
                                                float* __restrict__ zpart, int N) {
    const int q = blockIdx.y, cb = blockIdx.x;
    const int tid = threadIdx.x;
    const int n0 = cb * CHUNK, n1 = min(n0 + CHUNK, N);
    const int cnt = n1 - n0;
    __shared__ float wlds[256];
    __shared__ float zred[4];
    const float* s1q = s1 + (size_t)q * N;
    const float b2v = b2[0];

    float zp = 0.f;
    if (tid < cnt) {
        int n = n0 + tid;
        float acc = 0.f;
        #pragma unroll
        for (int k = 0; k < KN; ++k) acc += s1q[edges[(size_t)n * KN + k]];
        float sc = acc * 0.125f + b2v;
        score[(size_t)q * N + n] = sc;
        float ex = __expf(sc);
        wlds[tid] = ex;
        zp = ex;
    }
    float z = zp;
    #pragma unroll
    for (int off = 32; off; off >>= 1) z += __shfl_xor(z, off);
    if ((tid & 63) == 0) zred[tid >> 6] = z;
    __syncthreads();

    const int fi = tid & 31, g = tid >> 5;
    const float4* v = (const float4*)(values + (size_t)q * N * FIN);
    float4 acc = make_float4(0.f, 0.f, 0.f, 0.f);
    int n = n0 + g;
    for (; n + 56 < n1; n += 64) {
        int l = n - n0;
        float w0 = wlds[l],      w1 = wlds[l + 8],  w2 = wlds[l + 16], w3 = wlds[l + 24];
        float w4 = wlds[l + 32], w5 = wlds[l + 40], w6 = wlds[l + 48], w7 = wlds[l + 56];
        float4 v0 = v[(size_t)n * 32 + fi];
        float4 v1 = v[(size_t)(n + 8) * 32 + fi];
        float4 v2 = v[(size_t)(n + 16) * 32 + fi];
        float4 v3 = v[(size_t)(n + 24) * 32 + fi];
        float4 v4 = v[(size_t)(n + 32) * 32 + fi];
        float4 v5 = v[(size_t)(n + 40) * 32 + fi];
        float4 v6 = v[(size_t)(n + 48) * 32 + fi];
        float4 v7 = v[(size_t)(n + 56) * 32 + fi];
        acc.x = fmaf(w0, v0.x, acc.x); acc.y = fmaf(w0, v0.y, acc.y);
        acc.z = fmaf(w0, v0.z, acc.z); acc.w = fmaf(w0, v0.w, acc.w);
        acc.x = fmaf(w1, v1.x, acc.x); acc.y = fmaf(w1, v1.y, acc.y);
        acc.z = fmaf(w1, v1.z, acc.z); acc.w = fmaf(w1, v1.w, acc.w);
        acc.x = fmaf(w2, v2.x, acc.x); acc.y = fmaf(w2, v2.y, acc.y);
        acc.z = fmaf(w2, v2.z, acc.z); acc.w = fmaf(w2, v2.w, acc.w);
        acc.x = fmaf(w3, v3.x, acc.x); acc.y = fmaf(w3, v3.y, acc.y);
        acc.z = fmaf(w3, v3.z, acc.z); acc.w = fmaf(w3, v3.w, acc.w);
        acc.x = fmaf(w4, v4.x, acc.x); acc.y = fmaf(w4, v4.y, acc.y);
        acc.z = fmaf(w4, v4.z, acc.z); acc.w = fmaf(w4, v4.w, acc.w);
        acc.x = fmaf(w5, v5.x, acc.x); acc.y = fmaf(w5, v5.y, acc.y);
        acc.z = fmaf(w5, v5.z, acc.z); acc.w = fmaf(w5, v5.w, acc.w);
        acc.x = fmaf(w6, v6.x, acc.x); acc.y = fmaf(w6, v6.y, acc.y);
        acc.z = fmaf(w6, v6.z, acc.z); acc.w = fmaf(w6, v6.w, acc.w);
        acc.x = fmaf(w7, v7.x, acc.x); acc.y = fmaf(w7, v7.y, acc.y);
        acc.z = fmaf(w7, v7.z, acc.z); acc.w = fmaf(w7, v7.w, acc.w);
    }
    for (; n < n1; n += 8) {
        float ww = wlds[n - n0];
        float4 a = v[(size_t)n * 32 + fi];
        acc.x = fmaf(ww, a.x, acc.x);
        acc.y = fmaf(ww, a.y, acc.y);
        acc.z = fmaf(ww, a.z, acc.z);
        acc.w = fmaf(ww, a.w, acc.w);
    }
    __shared__ float4 part[256];
    part[tid] = acc;
    __syncthreads();
    if (tid < 32) {
        float4 a = part[tid];
        #pragma unroll
        for (int gg = 1; gg < 8; ++gg) {
            float4 b = part[gg * 32 + tid];
            a.x += b.x; a.y += b.y; a.z += b.z; a.w += b.w;
        }
        ((float4*)partial)[((size_t)q * CTXB + cb) * 32 + fi] = a;
    }
    if (tid == 0) zpart[(size_t)q * CTXB + cb] = zred[0] + zred[1] + zred[2] + zred[3];
}

// ---------------- Stage 4: ctx[q,f] = (Σ_cb partial[q,cb,f]) / (Σ_cb zpart[q,cb]) ----------------
__global__ __launch_bounds__(512) void k_final(const float* __restrict__ partial,
                                               const float* __restrict__ zpart,
                                               float* __restrict__ ctx) {
    const int q = blockIdx.x;
    const int tid = threadIdx.x;
    const int f = tid & 127, h = tid >> 7;
    const float* p = partial + (size_t)q * CTXB * FIN;
    float s = 0.f;
    for (int b = h; b < CTXB; b += 4) s += p[(size_t)b * FIN + f];
    __shared__ float red[512];
    __shared__ float zred[8];
    red[tid] = s;
    float z = (tid < CTXB) ? zpart[(size_t)q * CTXB + tid] : 0.f;
    #pragma unroll
    for (int off = 32; off; off >>= 1) z += __shfl_xor(z, off);
    if ((tid & 63) == 0) zred[tid >> 6] = z;
    __syncthreads();
    if (tid < 128) {
        float Zt = zred[0] + zred[1] + zred[2] + zred[3] +
                   zred[4] + zred[5] + zred[6] + zred[7];
        float t = red[tid] + red[tid + 128] + red[tid + 256] + red[tid + 384];
        ctx[q * FIN + f] = t * (1.f / Zt);
    }
}

extern "C" void kernel_launch(void* const* d_in, const int* in_sizes, int n_in,
                              void* d_out, int out_size, void* d_ws, size_t ws_size,
                              hipStream_t stream) {
    const float* query  = (const float*)d_in[0];
    const float* values = (const float*)d_in[1];
    const int*   edges  = (const int*)d_in[2];
    const float* W1     = (const float*)d_in[3];
    const float* b1     = (const float*)d_in[4];
    const float* W2     = (const float*)d_in[5];
    const float* b2     = (const float*)d_in[6];

    int N = in_sizes[2] / KN;                 // 50000
    int Q = in_sizes[0] / (N * FIN);          // 4

    float* out   = (float*)d_out;
    float* ctx   = out;                       // [Q,128]
    float* score = out + (size_t)Q * FIN;     // [Q,N]

    char* ws = (char*)d_ws;
    __half* y = (__half*)ws;                                    // [Q,N,64] f16
    size_t off = (size_t)Q * N * FOUT * sizeof(__half);
    float* s1    = (float*)(ws + off);  off += (size_t)Q * N * sizeof(float);
    float* part  = (float*)(ws + off);  off += (size_t)Q * CTXB * FIN * sizeof(float);
    float* zpart = (float*)(ws + off);                          // [Q,CTXB]

    dim3 g1((N + 127) / 128, Q);
    k_xw<<<g1, 256, 0, stream>>>(query, W1, y, N);
    dim3 g2((N + 31) / 32, Q);
    k_agg<<<g2, 256, 0, stream>>>(y, edges, b1, W2, s1, N);
    dim3 g3(CTXB, Q);
    k_ctx<<<g3, 256, 0, stream>>>(values, s1, edges, b2, score, part, zpart, N);
    k_final<<<Q, 512, 0, stream>>>(part, zpart, ctx);
}